// Round 19
// baseline (94.777 us; speedup 1.0000x reference)
//
#include <hip/hip_runtime.h>
#include <hip/hip_bf16.h>
#include <cmath>

#define BZ 8
#define PZ 8192
#define FZ 768
#define FI 256
#define M_TOTAL (BZ * PZ)   // 65536
#define BM 128
#define BN 256
#define BK 64
#define NKT (FZ / BK)       // 12
#define NB_TILE (BN * BK)   // 16384 elements = 32 KB per (nb, t) B-tile

typedef __bf16 bf16_t;
typedef __bf16 bf16x8 __attribute__((ext_vector_type(8)));
typedef float f32x4 __attribute__((ext_vector_type(4)));

#define AS1 __attribute__((address_space(1)))
#define AS3 __attribute__((address_space(3)))
#define FENCE asm volatile("" ::: "memory")

// ---------------- pack V_w / U_w into per-(nb,t)-tiled, pre-swizzled bf16 ----
// packed col pr = 32*j + 16*u + r  <->  orig o = 16*j + r  (u: 0=V, 1=U)
// Tile (nb = pr>>8, t): contiguous 32 KB; within it, row prl = pr&255,
// 16B-slot `slot` stored at phys slot^(prl&7)  ->  a LINEAR DMA copy into LDS
// yields the bank-conflict-free swizzled layout directly.
__global__ __launch_bounds__(128)
void pack_weights(const float* __restrict__ Vw,
                  const float* __restrict__ Uw,
                  bf16_t* __restrict__ Wc) {
    int s = blockIdx.x * 128 + threadIdx.x;      // 0..49151
    int pr = s / 96, idx = s % 96;               // 96 = NKT * 8 slots
    int t = idx >> 3, slot = idx & 7;
    int j = pr >> 5, u = (pr >> 4) & 1, r = pr & 15;
    const float* src = (u ? Uw : Vw) + (size_t)(j * 16 + r) * FZ + t * 64 + slot * 8;
    int nb = pr >> 8, prl = pr & 255;
    float4 f0 = *(const float4*)src;
    float4 f1 = *(const float4*)(src + 4);
    bf16x8 v;
    v[0] = (bf16_t)f0.x; v[1] = (bf16_t)f0.y; v[2] = (bf16_t)f0.z; v[3] = (bf16_t)f0.w;
    v[4] = (bf16_t)f1.x; v[5] = (bf16_t)f1.y; v[6] = (bf16_t)f1.z; v[7] = (bf16_t)f1.w;
    *(bf16x8*)&Wc[(size_t)(nb * NKT + t) * NB_TILE + prl * 64 + (slot ^ (prl & 7)) * 8] = v;
}

// ---------------- fused GEMM + gate + w-reduce -> partial logits ----------------
// 1024 blocks x 512 threads (8 waves = 4wm x 2wn; wave tile 32x128 = 2fm x 8fn
// of 16x16x32 frags). Same block tile (128x256), same 80 KB LDS, same R16/R18
// sync skeleton -- only the wave decomposition changes: 16 waves/CU (vs 8)
// for latency hiding. Sync: issue B(t+1) DMA THEN A(t+1) regs before
// compute(t); barrier; writeA (implicit full drain); vmcnt(0); barrier.
__global__ __launch_bounds__(512, 4)
void gemm_gate(const float* __restrict__ x, const bf16_t* __restrict__ Wc,
               const float* __restrict__ Vb, const float* __restrict__ Ub,
               const float* __restrict__ ww, float* __restrict__ part) {
    __shared__ bf16_t As[BM * BK] __attribute__((aligned(16)));      // 16 KB
    __shared__ bf16_t Bs[2][BN * BK] __attribute__((aligned(16)));   // 2x32 KB

    // XCD-aware remap (R2-proven): the 2 n-blocks of one m-tile share bid%8
    // -> same XCD L2. 1024 = 16 x 64, bijective.
    const int bid = blockIdx.x;
    const int nb = (bid >> 3) & 1;
    const int mt = (bid & 7) | ((bid >> 4) << 3);    // 0..511
    const int tid = threadIdx.x;
    const int l = tid & 63, wv = tid >> 6;           // 8 waves
    const int wm = wv >> 1, wn = wv & 1;             // 4M x 2N waves
    const int row0 = mt * BM;

    f32x4 acc[2][8] = {};                            // [fm][fn] 64 VGPR
    float4 areg[4];                                  // A(t+1) staging, 16 VGPR
    const bf16_t* WcB = Wc + (size_t)nb * NKT * NB_TILE;

    // A: 4 x dwordx4 fp32 loads for tile t (coalesced; 512 thr cover 128x64)
    auto issueA = [&](int t) {
        #pragma unroll
        for (int i = 0; i < 2; ++i) {
            int sidx = tid + i * 512;            // 0..1023
            int row = sidx >> 3, sl = sidx & 7;
            const float* gp = x + (size_t)(row0 + row) * FZ + t * BK + sl * 8;
            areg[2 * i]     = *(const float4*)gp;
            areg[2 * i + 1] = *(const float4*)(gp + 4);
        }
    };
    auto writeA = [&]() {
        #pragma unroll
        for (int i = 0; i < 2; ++i) {
            int sidx = tid + i * 512;
            int row = sidx >> 3, sl = sidx & 7;
            float4 f0 = areg[2 * i], f1 = areg[2 * i + 1];
            bf16x8 v;
            v[0] = (bf16_t)f0.x; v[1] = (bf16_t)f0.y; v[2] = (bf16_t)f0.z; v[3] = (bf16_t)f0.w;
            v[4] = (bf16_t)f1.x; v[5] = (bf16_t)f1.y; v[6] = (bf16_t)f1.z; v[7] = (bf16_t)f1.w;
            *(bf16x8*)&As[row * 64 + (sl ^ (row & 7)) * 8] = v;
        }
    };
    // B: 4 x 1KB linear DMA per wave (8 waves cover the 32 KB tile)
    auto issueB = [&](int t, int buf) {
        const bf16_t* src = WcB + (size_t)t * NB_TILE + wv * 2048 + l * 8;
        bf16_t* dst = &Bs[buf][wv * 2048];
        #pragma unroll
        for (int c = 0; c < 4; ++c)
            __builtin_amdgcn_global_load_lds(
                (const AS1 void*)(src + c * 512),
                (AS3 void*)(dst + c * 512), 16, 0, 0);
    };
    auto compute = [&](int buf) {
        #pragma unroll
        for (int kk = 0; kk < 2; ++kk) {
            int sg = kk * 4 + (l >> 4);          // 16B k-slot group (0-conflict)
            bf16x8 af[2];
            #pragma unroll
            for (int fm = 0; fm < 2; ++fm) {
                int row = wm * 32 + fm * 16 + (l & 15);
                af[fm] = *(const bf16x8*)&As[row * 64 + ((sg ^ (row & 7)) * 8)];
            }
            #pragma unroll
            for (int fn = 0; fn < 8; ++fn) {
                int col = wn * 128 + fn * 16 + (l & 15);
                bf16x8 bfr = *(const bf16x8*)&Bs[buf][col * 64 + ((sg ^ (col & 7)) * 8)];
                #pragma unroll
                for (int fm = 0; fm < 2; ++fm)
                    acc[fm][fn] = __builtin_amdgcn_mfma_f32_16x16x32_bf16(
                        af[fm], bfr, acc[fm][fn], 0, 0, 0);
            }
        }
    };

    // ---- prologue: fully stage tile 0 (R18 skeleton verbatim) ----
    issueB(0, 0);
    FENCE;                               // pin DMA-before-A-loads issue order
    issueA(0);
    FENCE;
    writeA();                            // waits vmcnt for areg automatically
    asm volatile("s_waitcnt vmcnt(0) lgkmcnt(0)" ::: "memory");
    __builtin_amdgcn_s_barrier();

    #pragma unroll
    for (int t = 0; t < NKT; ++t) {
        const int cur = t & 1;
        if (t + 1 < NKT) {
            issueB(t + 1, cur ^ 1);      // DMA -> other B buffer, flies during compute
            FENCE;
            issueA(t + 1);               // 4 loads -> regs, fly during compute
            FENCE;
        }
        compute(cur);
        if (t + 1 < NKT) {
            __builtin_amdgcn_s_barrier();    // all waves done reading As(t)
            writeA();                        // regs (landed during compute) -> As
            asm volatile("s_waitcnt vmcnt(0) lgkmcnt(0)" ::: "memory");
            __builtin_amdgcn_s_barrier();    // As(t+1) + Bs[cur^1](t+1) ready
        }
    }

    // ---- epilogue: gate + reduce (HW exp: v_exp_f32) ----
    // C/D 16x16: col = l&15, row = (l>>4)*4 + e. fn pairs (2q,2q+1) hold V/U
    // logits for the SAME orig output o in the SAME lane.
    const int c16 = l & 15;
    float vb[4], ub[4], wf[4];
    #pragma unroll
    for (int q = 0; q < 4; ++q) {
        int o = (nb * 8 + wn * 4 + q) * 16 + c16;
        vb[q] = Vb[o]; ub[q] = Ub[o]; wf[q] = ww[o];
    }
    const int slot = nb * 2 + wn;                // 4 disjoint partial slots
    #pragma unroll
    for (int fm = 0; fm < 2; ++fm) {
        #pragma unroll
        for (int e = 0; e < 4; ++e) {
            float partial = 0.f;
            #pragma unroll
            for (int q = 0; q < 4; ++q) {
                float zv = acc[fm][2 * q][e] + vb[q];
                float zu = acc[fm][2 * q + 1][e] + ub[q];
                float th = 1.f - 2.f / (__expf(2.f * zv) + 1.f);   // tanh(zv)
                float sg = 1.f / (1.f + __expf(-zu));              // sigmoid(zu)
                partial += th * sg * wf[q];
            }
            partial += __shfl_xor(partial, 1);
            partial += __shfl_xor(partial, 2);
            partial += __shfl_xor(partial, 4);
            partial += __shfl_xor(partial, 8);
            if (c16 == 0) {
                int r = row0 + wm * 32 + fm * 16 + (l >> 4) * 4 + e;
                part[(size_t)slot * M_TOTAL + r] = partial;
            }
        }
    }
}

// ---------------- softmax stage 1: per-chunk stats (64 blocks) ----------------
__global__ __launch_bounds__(1024)
void softmax_part(const float* __restrict__ part, const int* __restrict__ nonpad,
                  float* __restrict__ satt, float* __restrict__ stats) {
    __shared__ float red[16];
    const int b = blockIdx.x >> 3, c = blockIdx.x & 7;
    const int np = nonpad[b];
    const int p = c * 1024 + threadIdx.x;        // one position per thread
    const int tid = threadIdx.x;

    float s = 0.f;
    #pragma unroll
    for (int q = 0; q < 4; ++q) s += part[(size_t)q * M_TOTAL + b * PZ + p];
    satt[b * PZ + p] = s;
    const bool valid = p < np;

    float m = valid ? s : -3.4e38f;
    #pragma unroll
    for (int off = 32; off; off >>= 1) m = fmaxf(m, __shfl_xor(m, off));
    if ((tid & 63) == 0) red[tid >> 6] = m;
    __syncthreads();
    m = red[0];
    #pragma unroll
    for (int i = 1; i < 16; ++i) m = fmaxf(m, red[i]);
    __syncthreads();

    float e = valid ? __expf(s - m) : 0.f;
    #pragma unroll
    for (int off = 32; off; off >>= 1) e += __shfl_xor(e, off);
    if ((tid & 63) == 0) red[tid >> 6] = e;
    __syncthreads();
    if (tid == 0) {
        float S = red[0];
        #pragma unroll
        for (int i = 1; i < 16; ++i) S += red[i];
        stats[(b * 8 + c) * 2 + 0] = m;
        stats[(b * 8 + c) * 2 + 1] = S;
    }
}

// ------- softmax stage 2 (fused merge + write, 64 blocks) -------
__global__ __launch_bounds__(1024)
void softmax_write(const float* __restrict__ satt, const float* __restrict__ stats,
                   const int* __restrict__ nonpad, float* __restrict__ out) {
    __shared__ float gsh[2];
    const int b = blockIdx.x >> 3, c = blockIdx.x & 7;
    const int np = nonpad[b];
    const int p = c * 1024 + threadIdx.x;
    const int tid = threadIdx.x;

    if (tid < 64) {            // first wave merges (lanes 8..63 idle-safe)
        const int l = tid;
        float m = (l < 8) ? stats[(b * 8 + l) * 2 + 0] : -3.4e38f;
        float s = (l < 8) ? stats[(b * 8 + l) * 2 + 1] : 0.f;
        float M = m;
        #pragma unroll
        for (int off = 4; off; off >>= 1) M = fmaxf(M, __shfl_xor(M, off));
        float contrib = s * __expf(m - M);   // exp(-inf)=0 kills empty chunks
        #pragma unroll
        for (int off = 4; off; off >>= 1) contrib += __shfl_xor(contrib, off);
        if (l == 0) { gsh[0] = M; gsh[1] = 1.f / contrib; }
    }
    __syncthreads();
    const float M = gsh[0], inv = gsh[1];
    const float s = satt[b * PZ + p];
    out[b * PZ + p] = (p < np) ? __expf(s - M) * inv : 0.f;
}

extern "C" void kernel_launch(void* const* d_in, const int* in_sizes, int n_in,
                              void* d_out, int out_size, void* d_ws, size_t ws_size,
                              hipStream_t stream) {
    const float* x    = (const float*)d_in[0];
    const int* nonpad = (const int*)d_in[1];
    const float* V_w  = (const float*)d_in[2];
    const float* V_b  = (const float*)d_in[3];
    const float* U_w  = (const float*)d_in[4];
    const float* U_b  = (const float*)d_in[5];
    const float* w_w  = (const float*)d_in[6];
    // d_in[7] = w_b: uniform logit shift -> softmax-invariant, unused.

    char* wsp = (char*)d_ws;
    bf16_t* Wc   = (bf16_t*)wsp;                wsp += (size_t)512 * FZ * 2;    // 768 KB
    float* part  = (float*)wsp;                 wsp += (size_t)4 * M_TOTAL * 4; // 1 MB
    float* satt  = (float*)wsp;                 wsp += (size_t)M_TOTAL * 4;     // 256 KB
    float* stats = (float*)wsp;                                                 // 512 B
    float* out   = (float*)d_out;

    pack_weights<<<384, 128, 0, stream>>>(V_w, U_w, Wc);
    gemm_gate<<<1024, 512, 0, stream>>>(x, Wc, V_b, U_b, w_w, part);
    softmax_part<<<64, 1024, 0, stream>>>(part, nonpad, satt, stats);
    softmax_write<<<64, 1024, 0, stream>>>(satt, stats, nonpad, out);
}

// Round 20
// 79.398 us; speedup vs baseline: 1.1937x; 1.1937x over previous
//
#include <hip/hip_runtime.h>
#include <hip/hip_bf16.h>
#include <cmath>

#define BZ 8
#define PZ 8192
#define FZ 768
#define FI 256
#define M_TOTAL (BZ * PZ)   // 65536
#define BM 128
#define BN 256
#define BK 64
#define NKT (FZ / BK)       // 12
#define NB_TILE (BN * BK)   // 16384 elements = 32 KB per (nb, t) B-tile

typedef __bf16 bf16_t;
typedef __bf16 bf16x8 __attribute__((ext_vector_type(8)));
typedef float f32x4 __attribute__((ext_vector_type(4)));

#define AS1 __attribute__((address_space(1)))
#define AS3 __attribute__((address_space(3)))
#define FENCE asm volatile("" ::: "memory")

// ---------------- pack V_w / U_w into per-(nb,t)-tiled, pre-swizzled bf16 ----
// packed col pr = 32*j + 16*u + r  <->  orig o = 16*j + r  (u: 0=V, 1=U)
// Tile (nb = pr>>8, t): contiguous 32 KB; within it, row prl = pr&255,
// 16B-slot `slot` stored at phys slot^(prl&7)  ->  a LINEAR DMA copy into LDS
// yields the bank-conflict-free swizzled layout directly.
// Vectorized: one thread = one 8-element slot (float4 x2 -> bf16x8 store).
__global__ __launch_bounds__(128)
void pack_weights(const float* __restrict__ Vw,
                  const float* __restrict__ Uw,
                  bf16_t* __restrict__ Wc) {
    int s = blockIdx.x * 128 + threadIdx.x;      // 0..49151
    int pr = s / 96, idx = s % 96;               // 96 = NKT * 8 slots
    int t = idx >> 3, slot = idx & 7;
    int j = pr >> 5, u = (pr >> 4) & 1, r = pr & 15;
    const float* src = (u ? Uw : Vw) + (size_t)(j * 16 + r) * FZ + t * 64 + slot * 8;
    int nb = pr >> 8, prl = pr & 255;
    float4 f0 = *(const float4*)src;
    float4 f1 = *(const float4*)(src + 4);
    bf16x8 v;
    v[0] = (bf16_t)f0.x; v[1] = (bf16_t)f0.y; v[2] = (bf16_t)f0.z; v[3] = (bf16_t)f0.w;
    v[4] = (bf16_t)f1.x; v[5] = (bf16_t)f1.y; v[6] = (bf16_t)f1.z; v[7] = (bf16_t)f1.w;
    *(bf16x8*)&Wc[(size_t)(nb * NKT + t) * NB_TILE + prl * 64 + (slot ^ (prl & 7)) * 8] = v;
}

// ---------------- fused GEMM + gate + w-reduce -> partial logits ----------------
// Session champion (79.6 us wall): 1024 blocks x 256 threads (4 waves,
// 2wm x 2wn; wave tile 64x128 = 4fm x 8fn of 16x16x32 frags). As 16KB +
// Bs 2x32KB = 80 KB -> 2 blocks/CU. Sync: issue B(t+1) DMA THEN A(t+1) regs
// before compute(t); barrier; writeA (implicit full drain); vmcnt(0); barrier.
// Do NOT reorder A before B (R17: -6%); do NOT split waves finer (R19: spill);
// do NOT count the drains (R11/R14: race/regress). This is the 2-phase
// structural ceiling for this problem.
__global__ __launch_bounds__(256, 2)
void gemm_gate(const float* __restrict__ x, const bf16_t* __restrict__ Wc,
               const float* __restrict__ Vb, const float* __restrict__ Ub,
               const float* __restrict__ ww, float* __restrict__ part) {
    __shared__ bf16_t As[BM * BK] __attribute__((aligned(16)));      // 16 KB
    __shared__ bf16_t Bs[2][BN * BK] __attribute__((aligned(16)));   // 2x32 KB

    // XCD-aware remap (R2-proven): the 2 n-blocks of one m-tile share bid%8
    // -> same XCD L2. 1024 = 16 x 64, bijective.
    const int bid = blockIdx.x;
    const int nb = (bid >> 3) & 1;
    const int mt = (bid & 7) | ((bid >> 4) << 3);    // 0..511
    const int tid = threadIdx.x;
    const int l = tid & 63, wv = tid >> 6;
    const int wm = wv >> 1, wn = wv & 1;             // 2M x 2N waves
    const int row0 = mt * BM;

    f32x4 acc[4][8] = {};                            // [fm][fn] 128 VGPR
    float4 areg[8];                                  // A(t+1) staging regs
    const bf16_t* WcB = Wc + (size_t)nb * NKT * NB_TILE;

    auto issueA = [&](int t) {
        #pragma unroll
        for (int i = 0; i < 4; ++i) {
            int sidx = tid + i * 256;            // 0..1023
            int row = sidx >> 3, sl = sidx & 7;
            const float* gp = x + (size_t)(row0 + row) * FZ + t * BK + sl * 8;
            areg[2 * i]     = *(const float4*)gp;
            areg[2 * i + 1] = *(const float4*)(gp + 4);
        }
    };
    auto writeA = [&]() {
        #pragma unroll
        for (int i = 0; i < 4; ++i) {
            int sidx = tid + i * 256;
            int row = sidx >> 3, sl = sidx & 7;
            float4 f0 = areg[2 * i], f1 = areg[2 * i + 1];
            bf16x8 v;
            v[0] = (bf16_t)f0.x; v[1] = (bf16_t)f0.y; v[2] = (bf16_t)f0.z; v[3] = (bf16_t)f0.w;
            v[4] = (bf16_t)f1.x; v[5] = (bf16_t)f1.y; v[6] = (bf16_t)f1.z; v[7] = (bf16_t)f1.w;
            *(bf16x8*)&As[row * 64 + (sl ^ (row & 7)) * 8] = v;
        }
    };
    auto issueB = [&](int t, int buf) {
        const bf16_t* src = WcB + (size_t)t * NB_TILE + wv * 4096 + l * 8;
        bf16_t* dst = &Bs[buf][wv * 4096];
        #pragma unroll
        for (int c = 0; c < 8; ++c)
            __builtin_amdgcn_global_load_lds(
                (const AS1 void*)(src + c * 512),
                (AS3 void*)(dst + c * 512), 16, 0, 0);
    };
    auto compute = [&](int buf) {
        #pragma unroll
        for (int kk = 0; kk < 2; ++kk) {
            int sg = kk * 4 + (l >> 4);          // 16B k-slot group (0-conflict)
            bf16x8 af[4];
            #pragma unroll
            for (int fm = 0; fm < 4; ++fm) {
                int row = wm * 64 + fm * 16 + (l & 15);
                af[fm] = *(const bf16x8*)&As[row * 64 + ((sg ^ (row & 7)) * 8)];
            }
            #pragma unroll
            for (int fn = 0; fn < 8; ++fn) {
                int col = wn * 128 + fn * 16 + (l & 15);
                bf16x8 bfr = *(const bf16x8*)&Bs[buf][col * 64 + ((sg ^ (col & 7)) * 8)];
                #pragma unroll
                for (int fm = 0; fm < 4; ++fm)
                    acc[fm][fn] = __builtin_amdgcn_mfma_f32_16x16x32_bf16(
                        af[fm], bfr, acc[fm][fn], 0, 0, 0);
            }
        }
    };

    // ---- prologue: fully stage tile 0 ----
    issueB(0, 0);
    FENCE;                               // pin DMA-before-A-loads issue order
    issueA(0);
    FENCE;
    writeA();                            // waits vmcnt for areg automatically
    asm volatile("s_waitcnt vmcnt(0) lgkmcnt(0)" ::: "memory");
    __builtin_amdgcn_s_barrier();

    #pragma unroll
    for (int t = 0; t < NKT; ++t) {
        const int cur = t & 1;
        if (t + 1 < NKT) {
            issueB(t + 1, cur ^ 1);      // DMA -> other B buffer, flies during compute
            FENCE;
            issueA(t + 1);               // 8 loads -> regs, fly during compute
            FENCE;
        }
        compute(cur);
        if (t + 1 < NKT) {
            __builtin_amdgcn_s_barrier();    // all waves done reading As(t)
            writeA();                        // regs (landed during compute) -> As
            asm volatile("s_waitcnt vmcnt(0) lgkmcnt(0)" ::: "memory");
            __builtin_amdgcn_s_barrier();    // As(t+1) + Bs[cur^1](t+1) ready
        }
    }

    // ---- epilogue: gate + reduce (HW exp: v_exp_f32) ----
    // C/D 16x16: col = l&15, row = (l>>4)*4 + e. fn pairs (2q,2q+1) hold V/U
    // logits for the SAME orig output o in the SAME lane.
    const int c16 = l & 15;
    float vb[4], ub[4], wf[4];
    #pragma unroll
    for (int q = 0; q < 4; ++q) {
        int o = (nb * 8 + wn * 4 + q) * 16 + c16;
        vb[q] = Vb[o]; ub[q] = Ub[o]; wf[q] = ww[o];
    }
    const int slot = nb * 2 + wn;                // 4 disjoint partial slots
    #pragma unroll
    for (int fm = 0; fm < 4; ++fm) {
        #pragma unroll
        for (int e = 0; e < 4; ++e) {
            float partial = 0.f;
            #pragma unroll
            for (int q = 0; q < 4; ++q) {
                float zv = acc[fm][2 * q][e] + vb[q];
                float zu = acc[fm][2 * q + 1][e] + ub[q];
                float th = 1.f - 2.f / (__expf(2.f * zv) + 1.f);   // tanh(zv)
                float sg = 1.f / (1.f + __expf(-zu));              // sigmoid(zu)
                partial += th * sg * wf[q];
            }
            partial += __shfl_xor(partial, 1);
            partial += __shfl_xor(partial, 2);
            partial += __shfl_xor(partial, 4);
            partial += __shfl_xor(partial, 8);
            if (c16 == 0) {
                int r = row0 + wm * 64 + fm * 16 + (l >> 4) * 4 + e;
                part[(size_t)slot * M_TOTAL + r] = partial;
            }
        }
    }
}

// ---------------- softmax stage 1: per-chunk stats (64 blocks) ----------------
__global__ __launch_bounds__(1024)
void softmax_part(const float* __restrict__ part, const int* __restrict__ nonpad,
                  float* __restrict__ satt, float* __restrict__ stats) {
    __shared__ float red[16];
    const int b = blockIdx.x >> 3, c = blockIdx.x & 7;
    const int np = nonpad[b];
    const int p = c * 1024 + threadIdx.x;        // one position per thread
    const int tid = threadIdx.x;

    float s = 0.f;
    #pragma unroll
    for (int q = 0; q < 4; ++q) s += part[(size_t)q * M_TOTAL + b * PZ + p];
    satt[b * PZ + p] = s;
    const bool valid = p < np;

    float m = valid ? s : -3.4e38f;
    #pragma unroll
    for (int off = 32; off; off >>= 1) m = fmaxf(m, __shfl_xor(m, off));
    if ((tid & 63) == 0) red[tid >> 6] = m;
    __syncthreads();
    m = red[0];
    #pragma unroll
    for (int i = 1; i < 16; ++i) m = fmaxf(m, red[i]);
    __syncthreads();

    float e = valid ? __expf(s - m) : 0.f;
    #pragma unroll
    for (int off = 32; off; off >>= 1) e += __shfl_xor(e, off);
    if ((tid & 63) == 0) red[tid >> 6] = e;
    __syncthreads();
    if (tid == 0) {
        float S = red[0];
        #pragma unroll
        for (int i = 1; i < 16; ++i) S += red[i];
        stats[(b * 8 + c) * 2 + 0] = m;
        stats[(b * 8 + c) * 2 + 1] = S;
    }
}

// ------- softmax stage 2 (fused merge + write, 64 blocks) -------
// Each block redundantly merges its bag's 8 chunk-stats (16 floats -- free),
// then scales + writes its 1024 positions.
__global__ __launch_bounds__(1024)
void softmax_write(const float* __restrict__ satt, const float* __restrict__ stats,
                   const int* __restrict__ nonpad, float* __restrict__ out) {
    __shared__ float gsh[2];
    const int b = blockIdx.x >> 3, c = blockIdx.x & 7;
    const int np = nonpad[b];
    const int p = c * 1024 + threadIdx.x;
    const int tid = threadIdx.x;

    if (tid < 64) {            // first wave merges (lanes 8..63 idle-safe)
        const int l = tid;
        float m = (l < 8) ? stats[(b * 8 + l) * 2 + 0] : -3.4e38f;
        float s = (l < 8) ? stats[(b * 8 + l) * 2 + 1] : 0.f;
        float M = m;
        #pragma unroll
        for (int off = 4; off; off >>= 1) M = fmaxf(M, __shfl_xor(M, off));
        float contrib = s * __expf(m - M);   // exp(-inf)=0 kills empty chunks
        #pragma unroll
        for (int off = 4; off; off >>= 1) contrib += __shfl_xor(contrib, off);
        if (l == 0) { gsh[0] = M; gsh[1] = 1.f / contrib; }
    }
    __syncthreads();
    const float M = gsh[0], inv = gsh[1];
    const float s = satt[b * PZ + p];
    out[b * PZ + p] = (p < np) ? __expf(s - M) * inv : 0.f;
}

extern "C" void kernel_launch(void* const* d_in, const int* in_sizes, int n_in,
                              void* d_out, int out_size, void* d_ws, size_t ws_size,
                              hipStream_t stream) {
    const float* x    = (const float*)d_in[0];
    const int* nonpad = (const int*)d_in[1];
    const float* V_w  = (const float*)d_in[2];
    const float* V_b  = (const float*)d_in[3];
    const float* U_w  = (const float*)d_in[4];
    const float* U_b  = (const float*)d_in[5];
    const float* w_w  = (const float*)d_in[6];
    // d_in[7] = w_b: uniform logit shift -> softmax-invariant, unused.

    char* wsp = (char*)d_ws;
    bf16_t* Wc   = (bf16_t*)wsp;                wsp += (size_t)512 * FZ * 2;    // 768 KB
    float* part  = (float*)wsp;                 wsp += (size_t)4 * M_TOTAL * 4; // 1 MB
    float* satt  = (float*)wsp;                 wsp += (size_t)M_TOTAL * 4;     // 256 KB
    float* stats = (float*)wsp;                                                 // 512 B
    float* out   = (float*)d_out;

    pack_weights<<<384, 128, 0, stream>>>(V_w, U_w, Wc);
    gemm_gate<<<1024, 256, 0, stream>>>(x, Wc, V_b, U_b, w_w, part);
    softmax_part<<<64, 1024, 0, stream>>>(part, nonpad, satt, stats);
    softmax_write<<<64, 1024, 0, stream>>>(satt, stats, nonpad, out);
}